// Round 1
// baseline (503.578 us; speedup 1.0000x reference)
//
#include <hip/hip_runtime.h>

// CRAFT OHEM loss on MI355X.
// Exact 3-stage radix select (9/11/12-bit... actually 512/2048/1024-bin on float
// bit patterns, monotone for v>=0) for per-(sample,channel) top-k negative-loss
// sums, matching the reference's sort+cumsum tie semantics bit-exactly.

constexpr int   BATCH   = 32;
constexpr int   NPS     = 768 * 768;            // 589824 pixels per sample
constexpr int   CH2     = BATCH * 2;            // 64 (sample,channel) problems
constexpr long  PIX_ALL = (long)BATCH * NPS;    // 18,874,368
constexpr int   EPB     = 16384;                // pixels per block in data passes
constexpr int   BX      = NPS / EPB;            // 36 blocks per sample (exact)
constexpr float POS_THR_F = 0.1f;
constexpr unsigned TOPK_NO_POS = 500u;

// ---------------------------------------------------------------------------
// Pass 1: loss compute + positive stats + stage-1 histogram (512 bins = bits>>21)
// Optionally materializes loss values (sentinel -1.0f for positives) into ws.
// ---------------------------------------------------------------------------
__global__ __launch_bounds__(256) void k_pass1(
    const float4* __restrict__ pred4,
    const float4* __restrict__ reg4,
    const float4* __restrict__ aff4,
    unsigned* __restrict__ h1c, float* __restrict__ h1s,
    unsigned* __restrict__ pcnt, float* __restrict__ psum,
    float4* __restrict__ lossR4, float4* __restrict__ lossA4, int writeLoss)
{
    __shared__ unsigned sc0[512], sc1[512];
    __shared__ float    ss0[512], ss1[512];
    __shared__ unsigned wpc[8];
    __shared__ float    wps[8];
    for (int j = threadIdx.x; j < 512; j += 256) { sc0[j]=0u; sc1[j]=0u; ss0[j]=0.f; ss1[j]=0.f; }
    __syncthreads();

    const int  b    = blockIdx.y;
    const long base = (long)b * NPS + (long)blockIdx.x * EPB;
    unsigned pc0 = 0, pc1 = 0;
    float    ps0 = 0.f, ps1 = 0.f;

    for (int i = 0; i < EPB / 1024; ++i) {           // 16 iters, 4 pixels/thread/iter
        const long g  = base + (long)((i << 8) + threadIdx.x) * 4;
        const long g4 = g >> 2;
        const float4 r  = reg4[g4];
        const float4 a  = aff4[g4];
        const float4 pA = pred4[g >> 1];
        const float4 pB = pred4[(g >> 1) + 1];
        float4 lr, la;
#define DO_PIX(RR, AA, PG, PA, LR, LA) do {                                      \
        float d0 = (PG) - (RR); float v0 = d0 * d0;                              \
        if ((RR) >= POS_THR_F) { pc0++; ps0 += v0; LR = -1.0f; }                 \
        else { unsigned bt = __float_as_uint(v0);                                \
               unsigned ky = bt >> 21; if (ky > 511u) ky = 511u;                 \
               atomicAdd(&sc0[ky], 1u); unsafeAtomicAdd(&ss0[ky], v0); LR = v0; }\
        float d1 = (PA) - (AA); float v1 = d1 * d1;                              \
        if ((AA) >= POS_THR_F) { pc1++; ps1 += v1; LA = -1.0f; }                 \
        else { unsigned bt = __float_as_uint(v1);                                \
               unsigned ky = bt >> 21; if (ky > 511u) ky = 511u;                 \
               atomicAdd(&sc1[ky], 1u); unsafeAtomicAdd(&ss1[ky], v1); LA = v1; }\
    } while (0)
        DO_PIX(r.x, a.x, pA.x, pA.y, lr.x, la.x);
        DO_PIX(r.y, a.y, pA.z, pA.w, lr.y, la.y);
        DO_PIX(r.z, a.z, pB.x, pB.y, lr.z, la.z);
        DO_PIX(r.w, a.w, pB.z, pB.w, lr.w, la.w);
#undef DO_PIX
        if (writeLoss) { lossR4[g4] = lr; lossA4[g4] = la; }
    }
    __syncthreads();

    // flush histograms, skipping empty bins
    for (int j = threadIdx.x; j < 512; j += 256) {
        unsigned c0 = sc0[j];
        if (c0) { atomicAdd(&h1c[(b*2+0)*512 + j], c0); unsafeAtomicAdd(&h1s[(b*2+0)*512 + j], ss0[j]); }
        unsigned c1 = sc1[j];
        if (c1) { atomicAdd(&h1c[(b*2+1)*512 + j], c1); unsafeAtomicAdd(&h1s[(b*2+1)*512 + j], ss1[j]); }
    }
    // reduce positive stats: wave shuffle then cross-wave via LDS
    for (int o = 32; o > 0; o >>= 1) {
        pc0 += __shfl_down(pc0, o); ps0 += __shfl_down(ps0, o);
        pc1 += __shfl_down(pc1, o); ps1 += __shfl_down(ps1, o);
    }
    const int wid = threadIdx.x >> 6, lane = threadIdx.x & 63;
    if (lane == 0) { wpc[wid] = pc0; wps[wid] = ps0; wpc[4+wid] = pc1; wps[4+wid] = ps1; }
    __syncthreads();
    if (threadIdx.x == 0) {
        unsigned t0 = 0, t1 = 0; float s0 = 0.f, s1 = 0.f;
        for (int q = 0; q < 4; ++q) { t0 += wpc[q]; s0 += wps[q]; t1 += wpc[4+q]; s1 += wps[4+q]; }
        atomicAdd(&pcnt[b*2+0], t0); unsafeAtomicAdd(&psum[b*2+0], s0);
        atomicAdd(&pcnt[b*2+1], t1); unsafeAtomicAdd(&psum[b*2+1], s1);
    }
}

// ---------------------------------------------------------------------------
// Parallel suffix-select over NBINS count/sum bins: finds bin T with
// countAbove(T) < k <= countAbove(T)+cnt[T]; returns T, rem = k-countAbove,
// and (on thread 0) the double sum of bins strictly above T.
// Block must be 256 threads.
// ---------------------------------------------------------------------------
template<int NBINS>
__device__ __forceinline__ void block_suffix_select(
    const unsigned* __restrict__ cnt, const float* __restrict__ sums,
    unsigned k, unsigned& outBin, unsigned& outRem, double& outSum)
{
    constexpr int PER = NBINS / 256;
    const int t = threadIdx.x;
    unsigned lc[PER]; float lf[PER];
#pragma unroll
    for (int j = 0; j < PER; ++j) { lc[j] = cnt[t*PER + j]; lf[j] = sums[t*PER + j]; }
    unsigned lsum = 0;
#pragma unroll
    for (int j = 0; j < PER; ++j) lsum += lc[j];

    __shared__ unsigned part[256];
    __shared__ unsigned s_bin, s_rem;
    __shared__ double   wsum[4];
    part[t] = lsum;
    __syncthreads();
    for (int off = 1; off < 256; off <<= 1) {        // inclusive suffix scan
        unsigned v = (t + off < 256) ? part[t + off] : 0u;
        __syncthreads();
        part[t] += v;
        __syncthreads();
    }
    unsigned cum = (t + 1 < 256) ? part[t + 1] : 0u; // count in threads above me
#pragma unroll
    for (int j = PER - 1; j >= 0; --j) {             // bins high -> low
        unsigned c = lc[j];
        if (cum < k && k <= cum + c) { s_bin = (unsigned)(t * PER + j); s_rem = k - cum; }
        cum += c;
    }
    __syncthreads();
    const unsigned bin = s_bin, rem = s_rem;
    double ds = 0.0;
#pragma unroll
    for (int j = 0; j < PER; ++j)
        if ((unsigned)(t * PER + j) > bin) ds += (double)lf[j];
    for (int o = 32; o > 0; o >>= 1) ds += __shfl_down(ds, o);
    const int wid = t >> 6, lane = t & 63;
    if (lane == 0) wsum[wid] = ds;
    __syncthreads();
    if (t == 0) ds = wsum[0] + wsum[1] + wsum[2] + wsum[3];
    outBin = bin; outRem = rem; outSum = ds;
}

__global__ __launch_bounds__(256) void k_scan1(
    const unsigned* __restrict__ h1c, const float* __restrict__ h1s,
    const unsigned* __restrict__ pcnt, const float* __restrict__ psum,
    unsigned* __restrict__ T1, unsigned* __restrict__ rem1,
    unsigned* __restrict__ kk, float* __restrict__ posi, double* __restrict__ sAb1)
{
    const int idx = blockIdx.x;
    const unsigned p  = pcnt[idx];
    const unsigned nn = (unsigned)NPS - p;
    const unsigned k  = p ? ((nn < 3u*p) ? nn : 3u*p) : TOPK_NO_POS;
    if (threadIdx.x == 0) {
        kk[idx]   = k;
        posi[idx] = p ? (psum[idx] / (float)p) : 0.0f;
    }
    if (k == 0u) {
        if (threadIdx.x == 0) { T1[idx] = 0xFFFFFFFFu; rem1[idx] = 0u; sAb1[idx] = 0.0; }
        return;
    }
    unsigned bin, rem; double s;
    block_suffix_select<512>(h1c + idx*512, h1s + idx*512, k, bin, rem, s);
    if (threadIdx.x == 0) { T1[idx] = bin; rem1[idx] = rem; sAb1[idx] = s; }
}

// ---------------------------------------------------------------------------
// Pass 2: stage-2 histogram (bits[20:10], 2048 bins) for elements in bin T1.
// ---------------------------------------------------------------------------
__global__ __launch_bounds__(256) void k_pass2(
    const float4* __restrict__ pred4,
    const float4* __restrict__ reg4,
    const float4* __restrict__ aff4,
    const float4* __restrict__ lossR4, const float4* __restrict__ lossA4, int haveLoss,
    const unsigned* __restrict__ T1,
    unsigned* __restrict__ h2c, float* __restrict__ h2s)
{
    __shared__ unsigned sc0[2048], sc1[2048];
    __shared__ float    ss0[2048], ss1[2048];
    for (int j = threadIdx.x; j < 2048; j += 256) { sc0[j]=0u; sc1[j]=0u; ss0[j]=0.f; ss1[j]=0.f; }
    __syncthreads();

    const int  b   = blockIdx.y;
    const unsigned t1r = T1[b*2+0], t1a = T1[b*2+1];
    const long base = (long)b * NPS + (long)blockIdx.x * EPB;

    for (int i = 0; i < EPB / 1024; ++i) {
        const long g  = base + (long)((i << 8) + threadIdx.x) * 4;
        const long g4 = g >> 2;
        float4 vr, va;
        if (haveLoss) { vr = lossR4[g4]; va = lossA4[g4]; }
        else {
            const float4 r  = reg4[g4];
            const float4 a  = aff4[g4];
            const float4 pA = pred4[g >> 1];
            const float4 pB = pred4[(g >> 1) + 1];
            float d;
            d = pA.x - r.x; vr.x = (r.x >= POS_THR_F) ? -1.0f : d*d;
            d = pA.z - r.y; vr.y = (r.y >= POS_THR_F) ? -1.0f : d*d;
            d = pB.x - r.z; vr.z = (r.z >= POS_THR_F) ? -1.0f : d*d;
            d = pB.z - r.w; vr.w = (r.w >= POS_THR_F) ? -1.0f : d*d;
            d = pA.y - a.x; va.x = (a.x >= POS_THR_F) ? -1.0f : d*d;
            d = pA.w - a.y; va.y = (a.y >= POS_THR_F) ? -1.0f : d*d;
            d = pB.y - a.z; va.z = (a.z >= POS_THR_F) ? -1.0f : d*d;
            d = pB.w - a.w; va.w = (a.w >= POS_THR_F) ? -1.0f : d*d;
        }
#define DO2(V, T1V, SC, SS) do {                                              \
        if ((V) >= 0.0f) { unsigned bt = __float_as_uint(V);                  \
            if ((bt >> 21) == (T1V)) { unsigned ky = (bt >> 10) & 2047u;      \
                atomicAdd(&SC[ky], 1u); unsafeAtomicAdd(&SS[ky], (V)); } } } while (0)
        DO2(vr.x, t1r, sc0, ss0); DO2(vr.y, t1r, sc0, ss0);
        DO2(vr.z, t1r, sc0, ss0); DO2(vr.w, t1r, sc0, ss0);
        DO2(va.x, t1a, sc1, ss1); DO2(va.y, t1a, sc1, ss1);
        DO2(va.z, t1a, sc1, ss1); DO2(va.w, t1a, sc1, ss1);
#undef DO2
    }
    __syncthreads();
    for (int j = threadIdx.x; j < 2048; j += 256) {
        unsigned c0 = sc0[j];
        if (c0) { atomicAdd(&h2c[(b*2+0)*2048 + j], c0); unsafeAtomicAdd(&h2s[(b*2+0)*2048 + j], ss0[j]); }
        unsigned c1 = sc1[j];
        if (c1) { atomicAdd(&h2c[(b*2+1)*2048 + j], c1); unsafeAtomicAdd(&h2s[(b*2+1)*2048 + j], ss1[j]); }
    }
}

__global__ __launch_bounds__(256) void k_scan2(
    const unsigned* __restrict__ h2c, const float* __restrict__ h2s,
    const unsigned* __restrict__ T1, const unsigned* __restrict__ rem1,
    const double* __restrict__ sAb1,
    unsigned* __restrict__ T2, unsigned* __restrict__ rem2, double* __restrict__ sAb2)
{
    const int idx = blockIdx.x;
    const unsigned t1 = T1[idx];
    if (t1 == 0xFFFFFFFFu) {
        if (threadIdx.x == 0) { T2[idx] = 0xFFFFFFFFu; rem2[idx] = 0u; sAb2[idx] = 0.0; }
        return;
    }
    const unsigned k = rem1[idx];
    unsigned bin, rem; double s;
    block_suffix_select<2048>(h2c + idx*2048, h2s + idx*2048, k, bin, rem, s);
    if (threadIdx.x == 0) { T2[idx] = bin; rem2[idx] = rem; sAb2[idx] = sAb1[idx] + s; }
}

// ---------------------------------------------------------------------------
// Pass 3: stage-3 histogram (bits[9:0], 1024 bins) for elements matching T1,T2.
// ---------------------------------------------------------------------------
__global__ __launch_bounds__(256) void k_pass3(
    const float4* __restrict__ pred4,
    const float4* __restrict__ reg4,
    const float4* __restrict__ aff4,
    const float4* __restrict__ lossR4, const float4* __restrict__ lossA4, int haveLoss,
    const unsigned* __restrict__ T1, const unsigned* __restrict__ T2,
    unsigned* __restrict__ h3c, float* __restrict__ h3s)
{
    __shared__ unsigned sc0[1024], sc1[1024];
    __shared__ float    ss0[1024], ss1[1024];
    for (int j = threadIdx.x; j < 1024; j += 256) { sc0[j]=0u; sc1[j]=0u; ss0[j]=0.f; ss1[j]=0.f; }
    __syncthreads();

    const int b = blockIdx.y;
    // combined 22-bit prefix; sentinel (0xFFFFFFFF) can never match since
    // (bits>>10) <= 0xFDFFF for v < 1.0
    const unsigned hiR = (T1[b*2+0] << 11) | T2[b*2+0];
    const unsigned hiA = (T1[b*2+1] << 11) | T2[b*2+1];
    const long base = (long)b * NPS + (long)blockIdx.x * EPB;

    for (int i = 0; i < EPB / 1024; ++i) {
        const long g  = base + (long)((i << 8) + threadIdx.x) * 4;
        const long g4 = g >> 2;
        float4 vr, va;
        if (haveLoss) { vr = lossR4[g4]; va = lossA4[g4]; }
        else {
            const float4 r  = reg4[g4];
            const float4 a  = aff4[g4];
            const float4 pA = pred4[g >> 1];
            const float4 pB = pred4[(g >> 1) + 1];
            float d;
            d = pA.x - r.x; vr.x = (r.x >= POS_THR_F) ? -1.0f : d*d;
            d = pA.z - r.y; vr.y = (r.y >= POS_THR_F) ? -1.0f : d*d;
            d = pB.x - r.z; vr.z = (r.z >= POS_THR_F) ? -1.0f : d*d;
            d = pB.z - r.w; vr.w = (r.w >= POS_THR_F) ? -1.0f : d*d;
            d = pA.y - a.x; va.x = (a.x >= POS_THR_F) ? -1.0f : d*d;
            d = pA.w - a.y; va.y = (a.y >= POS_THR_F) ? -1.0f : d*d;
            d = pB.y - a.z; va.z = (a.z >= POS_THR_F) ? -1.0f : d*d;
            d = pB.w - a.w; va.w = (a.w >= POS_THR_F) ? -1.0f : d*d;
        }
#define DO3(V, HI, SC, SS) do {                                               \
        if ((V) >= 0.0f) { unsigned bt = __float_as_uint(V);                  \
            if ((bt >> 10) == (HI)) { unsigned ky = bt & 1023u;               \
                atomicAdd(&SC[ky], 1u); unsafeAtomicAdd(&SS[ky], (V)); } } } while (0)
        DO3(vr.x, hiR, sc0, ss0); DO3(vr.y, hiR, sc0, ss0);
        DO3(vr.z, hiR, sc0, ss0); DO3(vr.w, hiR, sc0, ss0);
        DO3(va.x, hiA, sc1, ss1); DO3(va.y, hiA, sc1, ss1);
        DO3(va.z, hiA, sc1, ss1); DO3(va.w, hiA, sc1, ss1);
#undef DO3
    }
    __syncthreads();
    for (int j = threadIdx.x; j < 1024; j += 256) {
        unsigned c0 = sc0[j];
        if (c0) { atomicAdd(&h3c[(b*2+0)*1024 + j], c0); unsafeAtomicAdd(&h3s[(b*2+0)*1024 + j], ss0[j]); }
        unsigned c1 = sc1[j];
        if (c1) { atomicAdd(&h3c[(b*2+1)*1024 + j], c1); unsafeAtomicAdd(&h3s[(b*2+1)*1024 + j], ss1[j]); }
    }
}

__global__ __launch_bounds__(256) void k_scan3(
    const unsigned* __restrict__ h3c, const float* __restrict__ h3s,
    const unsigned* __restrict__ T1, const unsigned* __restrict__ T2,
    const unsigned* __restrict__ rem2,
    const unsigned* __restrict__ kk, const float* __restrict__ posi,
    const double* __restrict__ sAb2,
    float* __restrict__ contrib)
{
    const int idx = blockIdx.x;
    const unsigned k = kk[idx];
    if (k == 0u) {
        if (threadIdx.x == 0) contrib[idx] = posi[idx];
        return;
    }
    const unsigned r = rem2[idx];
    unsigned bin, rem; double s;
    block_suffix_select<1024>(h3c + idx*1024, h3s + idx*1024, r, bin, rem, s);
    if (threadIdx.x == 0) {
        // all elements in the final bin share this exact bit pattern
        const float t = __uint_as_float((T1[idx] << 21) | (T2[idx] << 10) | bin);
        const double nega = (sAb2[idx] + s + (double)rem * (double)t) / (double)k;
        contrib[idx] = (float)((double)posi[idx] + nega);
    }
}

__global__ void k_reduce(const float* __restrict__ contrib, float* __restrict__ out)
{
    double v = (double)contrib[threadIdx.x];    // 64 threads, one wave
    for (int o = 32; o > 0; o >>= 1) v += __shfl_down(v, o);
    if (threadIdx.x == 0) out[0] = (float)(v / (double)BATCH);
}

// ---------------------------------------------------------------------------
extern "C" void kernel_launch(void* const* d_in, const int* in_sizes, int n_in,
                              void* d_out, int out_size, void* d_ws, size_t ws_size,
                              hipStream_t stream)
{
    (void)in_sizes; (void)n_in; (void)out_size;
    const float4* pred4 = (const float4*)d_in[0];
    const float4* reg4  = (const float4*)d_in[1];
    const float4* aff4  = (const float4*)d_in[2];

    char* w = (char*)d_ws;
    unsigned* h1c  = (unsigned*)w;                       // 64*512 u32
    unsigned* h2c  = h1c + (size_t)CH2 * 512;            // 64*2048
    unsigned* h3c  = h2c + (size_t)CH2 * 2048;           // 64*1024
    float*    h1s  = (float*)(h3c + (size_t)CH2 * 1024); // 64*512
    float*    h2s  = h1s + (size_t)CH2 * 512;            // 64*2048
    float*    h3s  = h2s + (size_t)CH2 * 2048;           // 64*1024
    unsigned* pcnt = (unsigned*)(h3s + (size_t)CH2 * 1024);
    float*    psum = (float*)(pcnt + CH2);
    unsigned* T1   = (unsigned*)(psum + CH2);
    unsigned* T2   = T1 + CH2;
    unsigned* rem1 = T2 + CH2;
    unsigned* rem2 = rem1 + CH2;
    unsigned* kk   = rem2 + CH2;
    float*    posi = (float*)(kk + CH2);
    float*    contrib = posi + CH2;
    double*   sAb1 = (double*)(contrib + CH2);           // 8B-aligned (offset mult of 8)
    double*   sAb2 = sAb1 + CH2;
    const size_t hdr_bytes = (size_t)((char*)(sAb2 + CH2) - w);  // ~1.84 MB

    const size_t loss_off   = (size_t)4 << 20;
    const size_t loss_bytes = (size_t)PIX_ALL * 2 * sizeof(float);
    const int haveLoss = (ws_size >= loss_off + loss_bytes) ? 1 : 0;
    float4* lossR4 = (float4*)(w + loss_off);
    float4* lossA4 = (float4*)(w + loss_off + (size_t)PIX_ALL * sizeof(float));

    hipMemsetAsync(d_ws, 0, hdr_bytes, stream);

    dim3 grid(BX, BATCH);
    k_pass1<<<grid, 256, 0, stream>>>(pred4, reg4, aff4, h1c, h1s, pcnt, psum,
                                      lossR4, lossA4, haveLoss);
    k_scan1<<<CH2, 256, 0, stream>>>(h1c, h1s, pcnt, psum, T1, rem1, kk, posi, sAb1);
    k_pass2<<<grid, 256, 0, stream>>>(pred4, reg4, aff4, lossR4, lossA4, haveLoss,
                                      T1, h2c, h2s);
    k_scan2<<<CH2, 256, 0, stream>>>(h2c, h2s, T1, rem1, sAb1, T2, rem2, sAb2);
    k_pass3<<<grid, 256, 0, stream>>>(pred4, reg4, aff4, lossR4, lossA4, haveLoss,
                                      T1, T2, h3c, h3s);
    k_scan3<<<CH2, 256, 0, stream>>>(h3c, h3s, T1, T2, rem2, kk, posi, sAb2, contrib);
    k_reduce<<<1, 64, 0, stream>>>(contrib, (float*)d_out);
}